// Round 18
// baseline (425.139 us; speedup 1.0000x reference)
//
#include <hip/hip_runtime.h>
#include <hip/hip_bf16.h>
#include <cstdint>
#include <cstddef>

// Problem constants (fixed by the reference)
#define BATCH 128
#define SEQ   512
#define DIM   1024
#define MROWS (BATCH * SEQ)          // 65536

typedef short short8 __attribute__((ext_vector_type(8)));
typedef __bf16 bf16x8 __attribute__((ext_vector_type(8)));
typedef float f32x4 __attribute__((ext_vector_type(4)));

// ---------- MFMA wrapper: accept either builtin signature (short8 or bf16x8) ----------
template <typename VA> struct other_frag { using type = bf16x8; };
template <> struct other_frag<bf16x8> { using type = short8; };

template <typename VA>
__device__ __forceinline__ auto try_mfma(VA a, VA b, f32x4 c, int)
    -> decltype(__builtin_amdgcn_mfma_f32_16x16x32_bf16(a, b, c, 0, 0, 0)) {
  return __builtin_amdgcn_mfma_f32_16x16x32_bf16(a, b, c, 0, 0, 0);
}
template <typename VA>
__device__ __forceinline__ f32x4 try_mfma(VA a, VA b, f32x4 c, long) {
  using O = typename other_frag<VA>::type;
  O a2 = __builtin_bit_cast(O, a);
  O b2 = __builtin_bit_cast(O, b);
  return __builtin_amdgcn_mfma_f32_16x16x32_bf16(a2, b2, c, 0, 0, 0);
}
__device__ __forceinline__ f32x4 mfma_bf16(short8 a, short8 b, f32x4 c) {
  return try_mfma(a, b, c, 0);
}

// ---------- helpers ----------
__device__ __forceinline__ unsigned short f32_to_bf16(float f) {
  union { float f; uint32_t u; } v; v.f = f;
  uint32_t u = v.u;
  u += 0x7FFFu + ((u >> 16) & 1u);   // round-to-nearest-even
  return (unsigned short)(u >> 16);
}

// 8 x f32 -> 8 x bf16 (RNE)
__device__ __forceinline__ short8 cvt8(f32x4 a, f32x4 b) {
  bf16x8 o;
  o[0] = (__bf16)a[0]; o[1] = (__bf16)a[1]; o[2] = (__bf16)a[2]; o[3] = (__bf16)a[3];
  o[4] = (__bf16)b[0]; o[5] = (__bf16)b[1]; o[6] = (__bf16)b[2]; o[7] = (__bf16)b[3];
  return __builtin_bit_cast(short8, o);
}

__device__ __forceinline__ void gload_lds16(const void* g, void* l) {
  __builtin_amdgcn_global_load_lds(
      (__attribute__((address_space(1))) void*)g,
      (__attribute__((address_space(3))) void*)l,
      16, 0, 0);
}

__device__ __forceinline__ float fast_tanh(float x) {
  x = fminf(fmaxf(x, -15.0f), 15.0f);
  float e = __expf(2.0f * x);
  return (e - 1.0f) / (e + 1.0f);
}

// ---------- kernel 1: W1 (D x D) -> W1t bf16 (transposed, [e][d]) ----------
__global__ __launch_bounds__(256) void w1t_kernel(const float* __restrict__ W1,
                                                  unsigned short* __restrict__ W1t) {
  __shared__ float tile[64][65];
  int bx = blockIdx.x & 15;    // e-tile
  int by = blockIdx.x >> 4;    // d-tile
  int t = threadIdx.x;
  int c = t & 63, r0 = t >> 6;
#pragma unroll
  for (int i = 0; i < 16; i++) {
    int r = i * 4 + r0;
    tile[r][c] = W1[(size_t)(by * 64 + r) * DIM + bx * 64 + c];
  }
  __syncthreads();
#pragma unroll
  for (int i = 0; i < 16; i++) {
    int r = i * 4 + r0;
    W1t[(size_t)(bx * 64 + r) * DIM + by * 64 + c] = f32_to_bf16(tile[c][r]);
  }
}

// ---------- kernel 2: 256x256 GEMM, 8-phase BK=64, fp32-A direct ----------
// C[m][e] = sum_d bf16(X[m][d]) * W1t[e][d]; scores[m] += sum_e tanh(C+b1[e])*w2[e]
//
// 8 waves (2M x 4N, wave tile 128x64).  K in tiles of 64 = 2 K32 sub-blocks.
// LDS = A fp32 2 x 64 KB [0,128K) + B bf16 1 x 32 KB [128K,160K) = 160 KB.
// ONLY the two empirically-0-conflict layouts are used (R17 lesson: novel
// XOR formulas conflict even when paper models pass):
//   A sub-block (32 KB, [256 rows][32 fp32]): addr = row*128 +
//     (q ^ (row&7) ^ ((row>>3)&7))*16   [R10/R14, measured 0 x3]
//   B sub-block (16 KB, row-pairs): addr = (row>>1)*128 +
//     (((row&1)*4 + k16) ^ ((row>>1)&7))*16   [R2/R4, measured 0 x3]
//
// Phases: ph Q reads A rows [Q*32,+32) (8 b128 + cvt) (+ all 8 B reads at
// ph0 into regs) || stage ops || barrier || 16 MFMA (setprio) || [ph3:
// vmcnt(2)] || barrier.
// A unit Uq = rows [q*32,+32) u [128+q*32,+32) (16 KB, read only at phase q).
// Staging (T steady): ph0: A(T+1)U1 -> bufA[(T+1)&1]; ph1: U2 + B(T+1)kk0;
// ph2: U3 + B(T+1)kk1; ph3: A(T+2)U0 -> bufA[T&1].  Every write lands >= 2
// barriers after its region's last read.  B single buffer: B(T) is fully in
// regs after ph0, so ph1/ph2 restage is safe.
// vmcnt queue at T ph3 (oldest->newest): U0(T+1)2,U12,(U2,B0)4,(U3,B1)4,
// U0(T+2)2 = 14 -> vmcnt(2) retires A(T+1)+B(T+1), keeps A(T+2)U0.
// Prologue: A(0) 8 + B(0) 4 + A(1)U0 2 -> vmcnt(2).  Tile14: vmcnt(0); tile15 bare.
__global__ __launch_bounds__(512, 2) void gemm_score_kernel(
    const float* __restrict__ X,              // [MROWS][DIM] fp32
    const unsigned short* __restrict__ W1t,   // [DIM][DIM]  (e-major) bf16
    const float* __restrict__ b1,
    const float* __restrict__ w2,
    float* __restrict__ scores) {             // [MROWS]
  __shared__ __align__(16) char lds[163840];

  const int tid = threadIdx.x;
  const int lane = tid & 63;
  const int w = tid >> 6;                     // wave 0..7
  const int wr = w >> 2, wc = w & 3;          // 2 x 4 wave grid, 128x64 each
  const int ln15 = lane & 15;
  const int h2 = (lane >> 4) * 2;

  // chunked XCD swizzle: 1024 blocks, 8 XCDs, n-fastest within each chunk
  const int bx = blockIdx.x;
  const int swz = (bx & 7) * 128 + (bx >> 3);
  const int m0 = (swz >> 2) * 256;
  const int n0 = (swz & 3) * 256;

  // ---- A staging (R10 inverse map).  Unit q, wave w covers 8 rows starting
  // at rb = q*32 + hw;  lane: row = rb + (lane>>3), stored granule = lane&7,
  // logical granule q_f = (lane&7) ^ (row&7) ^ ((row>>3)&7).
  const int hw = (w >> 2) * 128 + (w & 3) * 8;
  const float* pAU[4];
  int dAU[4];
#pragma unroll
  for (int q = 0; q < 4; q++) {
    int rb = q * 32 + hw;
    int row = rb + (lane >> 3);
    int qf = (lane & 7) ^ (row & 7) ^ ((row >> 3) & 7);
    pAU[q] = X + (size_t)(m0 + row) * DIM + qf * 4;
    dAU[q] = rb * 128;
  }

  // ---- B staging (R2 inverse map): sc = i*512 + tid
  const unsigned short* pB[2];
#pragma unroll
  for (int i = 0; i < 2; i++) {
    int sc = i * 512 + tid;
    int sr = sc >> 3;
    int j = (sc & 7) ^ (sr & 7);
    int row = sr * 2 + (j >> 2);
    pB[i] = W1t + (size_t)(n0 + row) * DIM + (j & 3) * 8;
  }

  // ---- B fragment LDS byte offsets (R2 read formula; kk1 = +16384)
  int bOff[4];
#pragma unroll
  for (int ni = 0; ni < 4; ni++) {
    int row = wc * 64 + ni * 16 + ln15;
    int sr = row >> 1;
    int js = ((row & 1) * 4 + (lane >> 4)) ^ (sr & 7);
    bOff[ni] = 131072 + sr * 128 + js * 16;
  }

  f32x4 acc[8][4];
#pragma unroll
  for (int mi = 0; mi < 8; mi++)
#pragma unroll
    for (int ni = 0; ni < 4; ni++)
      acc[mi][ni] = (f32x4){0.f, 0.f, 0.f, 0.f};

  short8 bfv[4][2];

#define ST_AU(T, AB, Q) do {                                            \
    gload_lds16(pAU[Q] + (T) * 64,      lds + (AB) * 65536 + dAU[Q]);   \
    gload_lds16(pAU[Q] + (T) * 64 + 32, lds + (AB) * 65536 + 32768 + dAU[Q]); \
  } while (0)
#define ST_B(T, KK) do {                                                \
    gload_lds16(pB[0] + (T) * 64 + (KK) * 32,                           \
                lds + 131072 + (KK) * 16384 + w * 1024);                \
    gload_lds16(pB[1] + (T) * 64 + (KK) * 32,                           \
                lds + 131072 + (KK) * 16384 + 8192 + w * 1024);         \
  } while (0)

  // A fragment read: (mi = 2Q+D, kk): fp32 8 floats -> bf16x8
#define AFRAG(Q, D, KK, ABASE, DST) do {                                \
    int row_ = wr * 128 + (2 * (Q) + (D)) * 16 + ln15;                  \
    int js_ = h2 ^ (row_ & 7) ^ ((row_ >> 3) & 7);                      \
    const char* p_ = lds + (ABASE) + (KK) * 32768 + row_ * 128;         \
    f32x4 lo_ = *(const f32x4*)(p_ + js_ * 16);                         \
    f32x4 hi_ = *(const f32x4*)(p_ + (js_ ^ 1) * 16);                   \
    DST = cvt8(lo_, hi_);                                               \
  } while (0)

#define WAIT2 asm volatile("s_waitcnt vmcnt(2)" ::: "memory")
#define WAIT0 asm volatile("s_waitcnt vmcnt(0)" ::: "memory")
#define NOWAIT do {} while (0)

#define PHASE(Q, ABASE, WAITOP, ...) do {                               \
    short8 a00_, a01_, a10_, a11_;                                      \
    AFRAG(Q, 0, 0, ABASE, a00_);                                        \
    AFRAG(Q, 0, 1, ABASE, a01_);                                        \
    AFRAG(Q, 1, 0, ABASE, a10_);                                        \
    AFRAG(Q, 1, 1, ABASE, a11_);                                        \
    if ((Q) == 0) {                                                     \
      _Pragma("unroll")                                                 \
      for (int ni = 0; ni < 4; ni++) {                                  \
        bfv[ni][0] = *(const short8*)(lds + bOff[ni]);                  \
        bfv[ni][1] = *(const short8*)(lds + bOff[ni] + 16384);          \
      }                                                                 \
    }                                                                   \
    __VA_ARGS__;                                                        \
    __builtin_amdgcn_s_barrier();                                       \
    __builtin_amdgcn_s_setprio(1);                                      \
    _Pragma("unroll")                                                   \
    for (int ni = 0; ni < 4; ni++) {                                    \
      acc[2 * (Q)][ni] = mfma_bf16(a00_, bfv[ni][0], acc[2 * (Q)][ni]); \
      acc[2 * (Q)][ni] = mfma_bf16(a01_, bfv[ni][1], acc[2 * (Q)][ni]); \
      acc[2 * (Q) + 1][ni] = mfma_bf16(a10_, bfv[ni][0], acc[2 * (Q) + 1][ni]); \
      acc[2 * (Q) + 1][ni] = mfma_bf16(a11_, bfv[ni][1], acc[2 * (Q) + 1][ni]); \
    }                                                                   \
    __builtin_amdgcn_s_setprio(0);                                      \
    WAITOP;                                                             \
    __builtin_amdgcn_s_barrier();                                       \
  } while (0)

#define TILE_FULL(T, BUF, OBUF) do {                                    \
    PHASE(0, (BUF) * 65536, NOWAIT, ST_AU((T) + 1, OBUF, 1));           \
    PHASE(1, (BUF) * 65536, NOWAIT, ST_AU((T) + 1, OBUF, 2); ST_B((T) + 1, 0)); \
    PHASE(2, (BUF) * 65536, NOWAIT, ST_AU((T) + 1, OBUF, 3); ST_B((T) + 1, 1)); \
    PHASE(3, (BUF) * 65536, WAIT2, ST_AU((T) + 2, BUF, 0));             \
  } while (0)

  // ---- prologue: A(0) all units, B(0) both halves, A(1)U0
  ST_AU(0, 0, 0); ST_AU(0, 0, 1); ST_AU(0, 0, 2); ST_AU(0, 0, 3);
  ST_B(0, 0); ST_B(0, 1);
  ST_AU(1, 1, 0);
  WAIT2;
  __builtin_amdgcn_s_barrier();

  // ---- main: tiles 0..13
  for (int t = 0; t < 7; ++t) {
    const int T0 = 2 * t;
    TILE_FULL(T0, 0, 1);
    TILE_FULL(T0 + 1, 1, 0);
  }
  // tile 14 (BUF 0, OBUF 1): stage A(15)U123 + B(15); drain at ph3
  PHASE(0, 0, NOWAIT, ST_AU(15, 1, 1));
  PHASE(1, 0, NOWAIT, ST_AU(15, 1, 2); ST_B(15, 0));
  PHASE(2, 0, NOWAIT, ST_AU(15, 1, 3); ST_B(15, 1));
  PHASE(3, 0, WAIT0, );
  // tile 15 (BUF 1): bare
  PHASE(0, 65536, NOWAIT, );
  PHASE(1, 65536, NOWAIT, );
  PHASE(2, 65536, NOWAIT, );
  PHASE(3, 65536, NOWAIT, );

#undef TILE_FULL
#undef PHASE
#undef AFRAG
#undef ST_AU
#undef ST_B

  // epilogue: scores[row] += sum over this wave's 64 cols of tanh(c + b1) * w2
  const int cg = lane >> 4;   // row group: rows cg*4 + j
  const int cl = lane & 15;   // col within fragment
#pragma unroll
  for (int mi = 0; mi < 8; mi++) {
    float p0 = 0.f, p1 = 0.f, p2 = 0.f, p3 = 0.f;
#pragma unroll
    for (int ni = 0; ni < 4; ni++) {
      int col = n0 + wc * 64 + ni * 16 + cl;
      float w2v = w2[col];
      float b1v = b1[col];
      p0 += fast_tanh(acc[mi][ni][0] + b1v) * w2v;
      p1 += fast_tanh(acc[mi][ni][1] + b1v) * w2v;
      p2 += fast_tanh(acc[mi][ni][2] + b1v) * w2v;
      p3 += fast_tanh(acc[mi][ni][3] + b1v) * w2v;
    }
#pragma unroll
    for (int off = 1; off < 16; off <<= 1) {
      p0 += __shfl_xor(p0, off);
      p1 += __shfl_xor(p1, off);
      p2 += __shfl_xor(p2, off);
      p3 += __shfl_xor(p3, off);
    }
    if (cl == 0) {
      int row = m0 + wr * 128 + mi * 16 + cg * 4;
      atomicAdd(&scores[row + 0], p0);
      atomicAdd(&scores[row + 1], p1);
      atomicAdd(&scores[row + 2], p2);
      atomicAdd(&scores[row + 3], p3);
    }
  }
}

// ---------- kernel 3: masked softmax + u_att + u_last (fp32 X) ----------
__global__ __launch_bounds__(256) void attn_uatt_kernel(
    const float* __restrict__ X,
    const float* __restrict__ scores,
    const int* __restrict__ mask,
    float* __restrict__ u_att,
    float* __restrict__ u_last) {
  const int b = blockIdx.x;
  const int half = blockIdx.y;            // d-range [half*512, half*512+512)
  const int tid = threadIdx.x;
  const int lane = tid & 63;
  const int wave = tid >> 6;

  __shared__ float attn[SEQ];
  __shared__ float rbuf[4];
  __shared__ float part[3][64 * 9];       // padded stride 9

  float s0 = scores[(size_t)b * SEQ + tid];
  float s1 = scores[(size_t)b * SEQ + 256 + tid];
  if (mask[(size_t)b * SEQ + tid]) s0 = -1000000000.0f;
  if (mask[(size_t)b * SEQ + 256 + tid]) s1 = -1000000000.0f;

  float mx = fmaxf(s0, s1);
#pragma unroll
  for (int off = 1; off < 64; off <<= 1) mx = fmaxf(mx, __shfl_xor(mx, off));
  if (lane == 0) rbuf[wave] = mx;
  __syncthreads();
  mx = fmaxf(fmaxf(rbuf[0], rbuf[1]), fmaxf(rbuf[2], rbuf[3]));

  float p0 = expf(s0 - mx), p1 = expf(s1 - mx);
  float sm = p0 + p1;
#pragma unroll
  for (int off = 1; off < 64; off <<= 1) sm += __shfl_xor(sm, off);
  __syncthreads();
  if (lane == 0) rbuf[wave] = sm;
  __syncthreads();
  sm = rbuf[0] + rbuf[1] + rbuf[2] + rbuf[3];
  float inv = 1.0f / sm;
  attn[tid] = p0 * inv;
  attn[tid + 256] = p1 * inv;
  __syncthreads();

  // u_last: exact fp32 copy of X[:, 511, :] (this block's 512-d half)
  if (tid < 128) {
    ((f32x4*)u_last)[(size_t)b * 256 + half * 128 + tid] =
        ((const f32x4*)X)[((size_t)b * SEQ + (SEQ - 1)) * 256 + half * 128 + tid];
  }

  // u_att[b][d] = sum_s attn[s] * X[b][s][d]; block covers 512 d (64 groups of 8)
  const int col = tid & 63;            // 8-float group within the half
  const int sh = tid >> 6;             // s-range split: [sh*128, sh*128+128)
  const f32x4* Xp = (const f32x4*)X + (size_t)b * SEQ * 256 + half * 128 + col * 2;
  f32x4 a0 = {0.f, 0.f, 0.f, 0.f}, a1 = {0.f, 0.f, 0.f, 0.f};
  for (int s = sh * 128; s < sh * 128 + 128; s++) {
    float wgt = attn[s];
    a0 += wgt * Xp[(size_t)s * 256];
    a1 += wgt * Xp[(size_t)s * 256 + 1];
  }
  if (sh) {
#pragma unroll
    for (int j = 0; j < 4; j++) part[sh - 1][col * 9 + j] = a0[j];
#pragma unroll
    for (int j = 0; j < 4; j++) part[sh - 1][col * 9 + 4 + j] = a1[j];
  }
  __syncthreads();
  if (sh == 0) {
#pragma unroll
    for (int j = 0; j < 4; j++)
      a0[j] += part[0][col * 9 + j] + part[1][col * 9 + j] + part[2][col * 9 + j];
#pragma unroll
    for (int j = 0; j < 4; j++)
      a1[j] += part[0][col * 9 + 4 + j] + part[1][col * 9 + 4 + j] + part[2][col * 9 + 4 + j];
    f32x4* dst = (f32x4*)(u_att + (size_t)b * DIM + half * 512 + col * 8);
    dst[0] = a0;
    dst[1] = a1;
  }
}

// ---------- launcher ----------
extern "C" void kernel_launch(void* const* d_in, const int* in_sizes, int n_in,
                              void* d_out, int out_size, void* d_ws, size_t ws_size,
                              hipStream_t stream) {
  const float* X    = (const float*)d_in[0];   // [128][512][1024] fp32
  const int*   mask = (const int*)d_in[1];     // [128][512] int32 (bool)
  const float* W1   = (const float*)d_in[2];   // [1024][1024]
  const float* b1   = (const float*)d_in[3];   // [1024]
  const float* w2   = (const float*)d_in[4];   // [1024]

  float* out    = (float*)d_out;
  float* u_last = out;                          // [128][1024]
  float* u_att  = out + BATCH * DIM;            // [128][1024]

  char* ws = (char*)d_ws;
  unsigned short* W1t = (unsigned short*)ws;                        // 2 MB
  float* scores = (float*)(ws + (size_t)DIM * DIM * 2);             // 256 KB

  hipMemsetAsync(scores, 0, MROWS * sizeof(float), stream);
  hipLaunchKernelGGL(w1t_kernel, dim3(256), dim3(256), 0, stream, W1, W1t);
  hipLaunchKernelGGL(gemm_score_kernel, dim3(1024), dim3(512), 0, stream,
                     X, W1t, b1, w2, scores);
  hipLaunchKernelGGL(attn_uatt_kernel, dim3(128, 2), dim3(256), 0, stream,
                     X, scores, mask, u_att, u_last);
}

// Round 19
// 228.455 us; speedup vs baseline: 1.8609x; 1.8609x over previous
//
#include <hip/hip_runtime.h>
#include <hip/hip_bf16.h>
#include <cstdint>
#include <cstddef>

// Problem constants (fixed by the reference)
#define BATCH 128
#define SEQ   512
#define DIM   1024
#define MROWS (BATCH * SEQ)          // 65536
#define NT    32                     // K sub-tiles of 32 (DIM/32)

typedef short short8 __attribute__((ext_vector_type(8)));
typedef __bf16 bf16x8 __attribute__((ext_vector_type(8)));
typedef float f32x4 __attribute__((ext_vector_type(4)));

// ---------- MFMA wrapper: accept either builtin signature (short8 or bf16x8) ----------
template <typename VA> struct other_frag { using type = bf16x8; };
template <> struct other_frag<bf16x8> { using type = short8; };

template <typename VA>
__device__ __forceinline__ auto try_mfma(VA a, VA b, f32x4 c, int)
    -> decltype(__builtin_amdgcn_mfma_f32_16x16x32_bf16(a, b, c, 0, 0, 0)) {
  return __builtin_amdgcn_mfma_f32_16x16x32_bf16(a, b, c, 0, 0, 0);
}
template <typename VA>
__device__ __forceinline__ f32x4 try_mfma(VA a, VA b, f32x4 c, long) {
  using O = typename other_frag<VA>::type;
  O a2 = __builtin_bit_cast(O, a);
  O b2 = __builtin_bit_cast(O, b);
  return __builtin_amdgcn_mfma_f32_16x16x32_bf16(a2, b2, c, 0, 0, 0);
}
__device__ __forceinline__ f32x4 mfma_bf16(short8 a, short8 b, f32x4 c) {
  return try_mfma(a, b, c, 0);
}

// ---------- helpers ----------
__device__ __forceinline__ unsigned short f32_to_bf16(float f) {
  union { float f; uint32_t u; } v; v.f = f;
  uint32_t u = v.u;
  u += 0x7FFFu + ((u >> 16) & 1u);   // round-to-nearest-even
  return (unsigned short)(u >> 16);
}

// 8 x f32 -> 8 x bf16 (RNE)
__device__ __forceinline__ short8 cvt8(f32x4 a, f32x4 b) {
  bf16x8 o;
  o[0] = (__bf16)a[0]; o[1] = (__bf16)a[1]; o[2] = (__bf16)a[2]; o[3] = (__bf16)a[3];
  o[4] = (__bf16)b[0]; o[5] = (__bf16)b[1]; o[6] = (__bf16)b[2]; o[7] = (__bf16)b[3];
  return __builtin_bit_cast(short8, o);
}

__device__ __forceinline__ void gload_lds16(const void* g, void* l) {
  __builtin_amdgcn_global_load_lds(
      (__attribute__((address_space(1))) void*)g,
      (__attribute__((address_space(3))) void*)l,
      16, 0, 0);
}

__device__ __forceinline__ float fast_tanh(float x) {
  x = fminf(fmaxf(x, -15.0f), 15.0f);
  float e = __expf(2.0f * x);
  return (e - 1.0f) / (e + 1.0f);
}

// ---------- kernel 1: W1 (D x D) -> W1t bf16 (transposed, [e][d]) ----------
__global__ __launch_bounds__(256) void w1t_kernel(const float* __restrict__ W1,
                                                  unsigned short* __restrict__ W1t) {
  __shared__ float tile[64][65];
  int bx = blockIdx.x & 15;    // e-tile
  int by = blockIdx.x >> 4;    // d-tile
  int t = threadIdx.x;
  int c = t & 63, r0 = t >> 6;
#pragma unroll
  for (int i = 0; i < 16; i++) {
    int r = i * 4 + r0;
    tile[r][c] = W1[(size_t)(by * 64 + r) * DIM + bx * 64 + c];
  }
  __syncthreads();
#pragma unroll
  for (int i = 0; i < 16; i++) {
    int r = i * 4 + r0;
    W1t[(size_t)(bx * 64 + r) * DIM + by * 64 + c] = f32_to_bf16(tile[c][r]);
  }
}

// ---------- kernel 2: 256x256-tile pipelined GEMM (fp32 A direct) ----------
// C[m][e] = sum_d bf16(X[m][d]) * W1t[e][d]; scores[m] += sum_e tanh(C+b1[e])*w2[e]
//
// FINAL (R14 configuration, empirical optimum of this search):
// 8 waves as 4Mx2N (wave tile 64x128): halves A-read duplication vs 2Mx4N
// (measured -9% gemm).  fp32 A staged direct from X via global_load_lds
// (no cast kernel); counted vmcnt(6) depth-2 + one raw s_barrier per
// K32-subtile; ring-3 buffers; XCD-chunked grid.  Both LDS layouts are the
// empirically-0-conflict ones (validated by the stride-8 bank model fitted
// over R1-R10 and confirmed by SQ_LDS_BANK_CONFLICT 1.678e7 -> 0):
//   A fp32 [256 rows][32 k]: 128-B stored row, granule js = q ^ (row&7) ^
//     ((row>>3)&7); ring-3 x 32 KB.  4 gloads/thread/subtile.
//   B bf16 row-pairs in 128-B stored rows, js = ((row&1)*4+k16) ^ (srow&7);
//     ring-3 x 16 KB.  2 gloads/thread/subtile.
// Staging writes LDS linearly (global_load_lds); global source applies the
// inverse permutation.  LDS total 144 KB.
//
// Post-search notes (why alternatives lost): bf16-A staging puts cvt+ds_write
// on the critical path (R13/R15); 128-tile 2-blk/CU raises duplication without
// adding waves (R16); 8-phase schedules hit novel-swizzle conflicts (R17) or
// VGPR-grant spill (R18); A-in-registers exceeds the 128-VGPR grant (R11/R12).
__global__ __launch_bounds__(512, 2) void gemm_score_kernel(
    const float* __restrict__ X,              // [MROWS][DIM] fp32
    const unsigned short* __restrict__ W1t,   // [DIM][DIM]  (e-major)
    const float* __restrict__ b1,
    const float* __restrict__ w2,
    float* __restrict__ scores) {             // [MROWS]
  __shared__ __align__(16) char lds[147456];  // A: [0,96K)  B: [96K,144K)

  const int tid = threadIdx.x;
  const int lane = tid & 63;
  const int w = tid >> 6;                     // wave 0..7
  const int wr = w >> 1, wc = w & 1;          // 4 x 2 wave grid, 64x128 each

  // chunked XCD swizzle: 1024 blocks, 8 XCDs, n-fastest within each chunk
  const int bx = blockIdx.x;
  const int swz = (bx & 7) * 128 + (bx >> 3);
  const int m0 = (swz >> 2) * 256;
  const int n0 = (swz & 3) * 256;

  // ---- A staging sources: 4 chunks/thread, sc = i*512 + tid.
  // row = sc>>3, js = sc&7, q = js ^ (row&7) ^ ((row>>3)&7).
  const float* aSrc[4];
#pragma unroll
  for (int i = 0; i < 4; i++) {
    int sc = i * 512 + tid;
    int row = sc >> 3;
    int q = (sc & 7) ^ (row & 7) ^ ((row >> 3) & 7);
    aSrc[i] = X + (size_t)(m0 + row) * DIM + q * 4;
  }
  // ---- B staging sources: 2 chunks/thread, sc = i*512 + tid (16B bf16 chunks)
  const unsigned short* bSrc[2];
#pragma unroll
  for (int i = 0; i < 2; i++) {
    int sc = i * 512 + tid;
    int srow = sc >> 3;
    int j = (sc & 7) ^ (srow & 7);
    int row = srow * 2 + (j >> 2);
    bSrc[i] = W1t + (size_t)(n0 + row) * DIM + (j & 3) * 8;
  }

  // ---- fragment LDS byte offsets
  // A: within a 32KB fp32 buffer; [mi][c], c = low/high f32x4 of the 8 floats
  int aOff[4][2];
#pragma unroll
  for (int mi = 0; mi < 4; mi++) {
    int row = wr * 64 + mi * 16 + (lane & 15);
    int m = (row & 7) ^ ((row >> 3) & 7);
#pragma unroll
    for (int c = 0; c < 2; c++) {
      int js = ((lane >> 4) * 2 + c) ^ m;
      aOff[mi][c] = row * 128 + js * 16;
    }
  }
  int bOff[8];                                // B: within a 16KB bf16 buffer
#pragma unroll
  for (int ni = 0; ni < 8; ni++) {
    int row = wc * 128 + ni * 16 + (lane & 15);
    int srow = row >> 1;
    int ic = ((row & 1) * 4 + (lane >> 4)) ^ (srow & 7);
    bOff[ni] = srow * 128 + ic * 16;
  }

  f32x4 acc[4][8];
#pragma unroll
  for (int mi = 0; mi < 4; mi++)
#pragma unroll
    for (int ni = 0; ni < 8; ni++)
      acc[mi][ni] = (f32x4){0.f, 0.f, 0.f, 0.f};

  short8 af[4], bfv[8];

#define STAGE(S) do {                                                   \
    const int bufA_ = ((S) % 3) * 32768;                                \
    const int bufB_ = 98304 + ((S) % 3) * 16384;                        \
    const int koF_ = (S) * 32;                                          \
    gload_lds16(aSrc[0] + koF_, lds + bufA_ + w * 1024);                \
    gload_lds16(aSrc[1] + koF_, lds + bufA_ + 8192 + w * 1024);         \
    gload_lds16(aSrc[2] + koF_, lds + bufA_ + 16384 + w * 1024);        \
    gload_lds16(aSrc[3] + koF_, lds + bufA_ + 24576 + w * 1024);        \
    gload_lds16(bSrc[0] + koF_, lds + bufB_ + w * 1024);                \
    gload_lds16(bSrc[1] + koF_, lds + bufB_ + 8192 + w * 1024);         \
  } while (0)

#define KITER(S, VMSTR) do {                                            \
    asm volatile("s_waitcnt vmcnt(" VMSTR ")" ::: "memory");            \
    __builtin_amdgcn_s_barrier();                                       \
    __builtin_amdgcn_sched_barrier(0);                                  \
    if ((S) + 2 < NT) STAGE((S) + 2);                                   \
    const char* bufA_ = lds + ((S) % 3) * 32768;                        \
    const char* bufB_ = lds + 98304 + ((S) % 3) * 16384;                \
    _Pragma("unroll")                                                   \
    for (int mi = 0; mi < 4; mi++) {                                    \
      f32x4 lo_ = *(const f32x4*)(bufA_ + aOff[mi][0]);                 \
      f32x4 hi_ = *(const f32x4*)(bufA_ + aOff[mi][1]);                 \
      af[mi] = cvt8(lo_, hi_);                                          \
    }                                                                   \
    _Pragma("unroll")                                                   \
    for (int ni = 0; ni < 8; ni++)                                      \
      bfv[ni] = *(const short8*)(bufB_ + bOff[ni]);                     \
    __builtin_amdgcn_s_setprio(1);                                      \
    _Pragma("unroll")                                                   \
    for (int mi = 0; mi < 4; mi++)                                      \
      _Pragma("unroll")                                                 \
      for (int ni = 0; ni < 8; ni++)                                    \
        acc[mi][ni] = mfma_bf16(af[mi], bfv[ni], acc[mi][ni]);          \
    __builtin_amdgcn_s_setprio(0);                                      \
  } while (0)

  // prologue: 2 sub-tiles in flight (12 wave-loads)
  STAGE(0); STAGE(1);

  for (int s = 0; s < NT - 1; ++s) KITER(s, "6");
  KITER(NT - 1, "0");

#undef STAGE
#undef KITER

  // epilogue: scores[row] += sum over this wave's 128 cols of tanh(c + b1) * w2
  const int cg = lane >> 4;   // row group: rows cg*4 + j
  const int cl = lane & 15;   // col within fragment
#pragma unroll
  for (int mi = 0; mi < 4; mi++) {
    float p0 = 0.f, p1 = 0.f, p2 = 0.f, p3 = 0.f;
#pragma unroll
    for (int ni = 0; ni < 8; ni++) {
      int col = n0 + wc * 128 + ni * 16 + cl;
      float w2v = w2[col];
      float b1v = b1[col];
      p0 += fast_tanh(acc[mi][ni][0] + b1v) * w2v;
      p1 += fast_tanh(acc[mi][ni][1] + b1v) * w2v;
      p2 += fast_tanh(acc[mi][ni][2] + b1v) * w2v;
      p3 += fast_tanh(acc[mi][ni][3] + b1v) * w2v;
    }
#pragma unroll
    for (int off = 1; off < 16; off <<= 1) {
      p0 += __shfl_xor(p0, off);
      p1 += __shfl_xor(p1, off);
      p2 += __shfl_xor(p2, off);
      p3 += __shfl_xor(p3, off);
    }
    if (cl == 0) {
      int row = m0 + wr * 64 + mi * 16 + cg * 4;
      atomicAdd(&scores[row + 0], p0);
      atomicAdd(&scores[row + 1], p1);
      atomicAdd(&scores[row + 2], p2);
      atomicAdd(&scores[row + 3], p3);
    }
  }
}

// ---------- kernel 3: masked softmax + u_att + u_last (fp32 X) ----------
__global__ __launch_bounds__(256) void attn_uatt_kernel(
    const float* __restrict__ X,
    const float* __restrict__ scores,
    const int* __restrict__ mask,
    float* __restrict__ u_att,
    float* __restrict__ u_last) {
  const int b = blockIdx.x;
  const int half = blockIdx.y;            // d-range [half*512, half*512+512)
  const int tid = threadIdx.x;
  const int lane = tid & 63;
  const int wave = tid >> 6;

  __shared__ float attn[SEQ];
  __shared__ float rbuf[4];
  __shared__ float part[3][64 * 9];       // padded stride 9

  float s0 = scores[(size_t)b * SEQ + tid];
  float s1 = scores[(size_t)b * SEQ + 256 + tid];
  if (mask[(size_t)b * SEQ + tid]) s0 = -1000000000.0f;
  if (mask[(size_t)b * SEQ + 256 + tid]) s1 = -1000000000.0f;

  float mx = fmaxf(s0, s1);
#pragma unroll
  for (int off = 1; off < 64; off <<= 1) mx = fmaxf(mx, __shfl_xor(mx, off));
  if (lane == 0) rbuf[wave] = mx;
  __syncthreads();
  mx = fmaxf(fmaxf(rbuf[0], rbuf[1]), fmaxf(rbuf[2], rbuf[3]));

  float p0 = expf(s0 - mx), p1 = expf(s1 - mx);
  float sm = p0 + p1;
#pragma unroll
  for (int off = 1; off < 64; off <<= 1) sm += __shfl_xor(sm, off);
  __syncthreads();
  if (lane == 0) rbuf[wave] = sm;
  __syncthreads();
  sm = rbuf[0] + rbuf[1] + rbuf[2] + rbuf[3];
  float inv = 1.0f / sm;
  attn[tid] = p0 * inv;
  attn[tid + 256] = p1 * inv;
  __syncthreads();

  // u_last: exact fp32 copy of X[:, 511, :] (this block's 512-d half)
  if (tid < 128) {
    ((f32x4*)u_last)[(size_t)b * 256 + half * 128 + tid] =
        ((const f32x4*)X)[((size_t)b * SEQ + (SEQ - 1)) * 256 + half * 128 + tid];
  }

  // u_att[b][d] = sum_s attn[s] * X[b][s][d]; block covers 512 d (64 groups of 8)
  const int col = tid & 63;            // 8-float group within the half
  const int sh = tid >> 6;             // s-range split: [sh*128, sh*128+128)
  const f32x4* Xp = (const f32x4*)X + (size_t)b * SEQ * 256 + half * 128 + col * 2;
  f32x4 a0 = {0.f, 0.f, 0.f, 0.f}, a1 = {0.f, 0.f, 0.f, 0.f};
  for (int s = sh * 128; s < sh * 128 + 128; s++) {
    float wgt = attn[s];
    a0 += wgt * Xp[(size_t)s * 256];
    a1 += wgt * Xp[(size_t)s * 256 + 1];
  }
  if (sh) {
#pragma unroll
    for (int j = 0; j < 4; j++) part[sh - 1][col * 9 + j] = a0[j];
#pragma unroll
    for (int j = 0; j < 4; j++) part[sh - 1][col * 9 + 4 + j] = a1[j];
  }
  __syncthreads();
  if (sh == 0) {
#pragma unroll
    for (int j = 0; j < 4; j++)
      a0[j] += part[0][col * 9 + j] + part[1][col * 9 + j] + part[2][col * 9 + j];
#pragma unroll
    for (int j = 0; j < 4; j++)
      a1[j] += part[0][col * 9 + 4 + j] + part[1][col * 9 + 4 + j] + part[2][col * 9 + 4 + j];
    f32x4* dst = (f32x4*)(u_att + (size_t)b * DIM + half * 512 + col * 8);
    dst[0] = a0;
    dst[1] = a1;
  }
}

// ---------- launcher ----------
extern "C" void kernel_launch(void* const* d_in, const int* in_sizes, int n_in,
                              void* d_out, int out_size, void* d_ws, size_t ws_size,
                              hipStream_t stream) {
  const float* X    = (const float*)d_in[0];   // [128][512][1024] fp32
  const int*   mask = (const int*)d_in[1];     // [128][512] int32 (bool)
  const float* W1   = (const float*)d_in[2];   // [1024][1024]
  const float* b1   = (const float*)d_in[3];   // [1024]
  const float* w2   = (const float*)d_in[4];   // [1024]

  float* out    = (float*)d_out;
  float* u_last = out;                          // [128][1024]
  float* u_att  = out + BATCH * DIM;            // [128][1024]

  char* ws = (char*)d_ws;
  unsigned short* W1t = (unsigned short*)ws;                        // 2 MB
  float* scores = (float*)(ws + (size_t)DIM * DIM * 2);             // 256 KB

  hipMemsetAsync(scores, 0, MROWS * sizeof(float), stream);
  hipLaunchKernelGGL(w1t_kernel, dim3(256), dim3(256), 0, stream, W1, W1t);
  hipLaunchKernelGGL(gemm_score_kernel, dim3(1024), dim3(512), 0, stream,
                     X, W1t, b1, w2, scores);
  hipLaunchKernelGGL(attn_uatt_kernel, dim3(128, 2), dim3(256), 0, stream,
                     X, scores, mask, u_att, u_last);
}